// Round 8
// baseline (667.960 us; speedup 1.0000x reference)
//
#include <hip/hip_runtime.h>
#include <hip/hip_bf16.h>
#include <cmath>

// SparseAttentionBlock: B=2, L=4096, D=512, H=8, dh=64
// Inputs/outputs fp32; internal GEMM pipeline bf16; residual spine fp32.
// Attention: S^T = K·Q^T trick -> P^T C-layout IS the 16x16x16 PV B-fragment.
// No LDS, no shuffles, no atomics in the K-loop.

#define L_SEQ 4096
#define D_MODEL 512
#define N_HEADS 8
#define D_HEAD 64
#define QKV_LD 1536

typedef __attribute__((ext_vector_type(8))) short bf16x8;
typedef __attribute__((ext_vector_type(4))) short bf16x4;
typedef __attribute__((ext_vector_type(4))) float f32x4;

__device__ __forceinline__ __hip_bfloat16 f2bf(float v) { return __float2bfloat16(v); }
__device__ __forceinline__ float bf2f(__hip_bfloat16 v) { return __bfloat162float(v); }
__device__ __forceinline__ short bfbits(float v) {
  __hip_bfloat16 t = __float2bfloat16(v);
  return *(short*)&t;
}

__device__ __forceinline__ void gl_lds16(const __hip_bfloat16* g, __hip_bfloat16* l) {
  __builtin_amdgcn_global_load_lds((__attribute__((address_space(1))) void*)g,
                                   (__attribute__((address_space(3))) void*)l, 16, 0, 0);
}

// ---------------- fp32 -> bf16 convert (weights) ----------------
__global__ __launch_bounds__(256) void cvt_kernel(const float* __restrict__ src,
                                                  __hip_bfloat16* __restrict__ dst, int n4) {
  const int i = blockIdx.x * 256 + threadIdx.x;
  if (i < n4) {
    const float4 v = ((const float4*)src)[i];
    dst[4 * i + 0] = f2bf(v.x);
    dst[4 * i + 1] = f2bf(v.y);
    dst[4 * i + 2] = f2bf(v.z);
    dst[4 * i + 3] = f2bf(v.w);
  }
}

// ---------------- LayerNorm: fp32 in -> bf16 out ----------------
__global__ __launch_bounds__(256) void ln_kernel(const float* __restrict__ x,
                                                 const float* __restrict__ g,
                                                 const float* __restrict__ b,
                                                 __hip_bfloat16* __restrict__ out) {
  const int row = blockIdx.x;
  const int t = threadIdx.x;
  const float* xr = x + (size_t)row * D_MODEL;
  float v0 = xr[t];
  float v1 = xr[t + 256];
  float s = v0 + v1;
  float qq = v0 * v0 + v1 * v1;
  for (int off = 32; off > 0; off >>= 1) {
    s += __shfl_xor(s, off);
    qq += __shfl_xor(qq, off);
  }
  __shared__ float red[8];
  const int wid = t >> 6;
  if ((t & 63) == 0) { red[wid] = s; red[4 + wid] = qq; }
  __syncthreads();
  s = red[0] + red[1] + red[2] + red[3];
  qq = red[4] + red[5] + red[6] + red[7];
  const float mu = s * (1.0f / 512.0f);
  const float var = fmaxf(qq * (1.0f / 512.0f) - mu * mu, 0.0f);
  const float rstd = rsqrtf(var + 1e-5f);
  __hip_bfloat16* orow = out + (size_t)row * D_MODEL;
  orow[t] = f2bf((v0 - mu) * rstd * g[t] + b[t]);
  orow[t + 256] = f2bf((v1 - mu) * rstd * g[t + 256] + b[t + 256]);
}

// ---------------- V transpose: qkv V-region -> vt[b,h,dh,L] ----------------
__global__ __launch_bounds__(256) void vtrans_kernel(const __hip_bfloat16* __restrict__ qkv,
                                                     __hip_bfloat16* __restrict__ vt) {
  const int gid = blockIdx.x * 256 + threadIdx.x;  // 2*64*4096 threads exactly
  const int l = gid & 4095;
  const int bg = gid >> 12;
  const int b = bg >> 6, g = bg & 63;
  const int h = g >> 3, dg = (g & 7) * 8;
  const __hip_bfloat16* src = qkv + (size_t)(b * L_SEQ + l) * QKV_LD + 1024 + h * 64 + dg;
  bf16x8 v = *(const bf16x8*)src;
  const size_t dbase = (size_t)((b * 8 + h) * 64 + dg) * L_SEQ + l;
  for (int j = 0; j < 8; j++)
    vt[dbase + (size_t)j * L_SEQ] = ((const __hip_bfloat16*)&v)[j];  // coalesced over l
}

// ---------------- kmax: per (b,h) max ||k_row||_2 ----------------
__global__ __launch_bounds__(256) void kmax_kernel(const __hip_bfloat16* __restrict__ qkv,
                                                   float* __restrict__ kmax) {
  const int bh = blockIdx.x;
  const int b = bh >> 3, h = bh & 7;
  const __hip_bfloat16* Kb = qkv + (size_t)b * L_SEQ * QKV_LD + 512 + h * 64;
  float mx = 0.f;
  for (int l = threadIdx.x; l < L_SEQ; l += 256) {
    const bf16x8* row = (const bf16x8*)(Kb + (size_t)l * QKV_LD);
    float ss = 0.f;
    for (int i = 0; i < 8; i++) {
      bf16x8 v = row[i];
      for (int k = 0; k < 8; k++) {
        const float f = bf2f(((const __hip_bfloat16*)&v)[k]);
        ss = fmaf(f, f, ss);
      }
    }
    mx = fmaxf(mx, ss);
  }
  for (int off = 32; off > 0; off >>= 1) mx = fmaxf(mx, __shfl_xor(mx, off));
  __shared__ float red[4];
  if ((threadIdx.x & 63) == 0) red[threadIdx.x >> 6] = mx;
  __syncthreads();
  if (threadIdx.x == 0)
    kmax[bh] = sqrtf(fmaxf(fmaxf(red[0], red[1]), fmaxf(red[2], red[3])));
}

// ---------------- key bias: bias[bh][l] = mask ? dfac_h * ts : -1e30 ----------------
__global__ __launch_bounds__(256) void bias_kernel(const float* __restrict__ ts,
                                                   const float* __restrict__ mask,
                                                   const float* __restrict__ decay_rate,
                                                   float* __restrict__ bias) {
  const int idx = blockIdx.x * 256 + threadIdx.x;  // 16*4096 threads
  const int bh = idx >> 12, l = idx & 4095;
  const int b = bh >> 3, h = bh & 7;
  const float LOG2E = 1.4426950408889634f;
  const float dfac = log1pf(expf(decay_rate[h])) * (1.0f / 24.0f) * LOG2E;
  const float m = mask[b * L_SEQ + l];
  bias[idx] = (m != 0.f) ? dfac * ts[b * L_SEQ + l] : -1e30f;
}

// ---------------- GEMM: C[M,N] = A[M,K] @ B[N,K]^T, bf16 in, fp32 accum ----------------
// EPI 0: store bf16   1: += aux(fp32), store fp32   2: silu, store bf16   3: += aux(fp32), store fp32
template <int EPI>
__global__ __launch_bounds__(256) void gemm_kernel(const __hip_bfloat16* __restrict__ A,
                                                   const __hip_bfloat16* __restrict__ B,
                                                   int M, int N, int K,
                                                   const float* __restrict__ aux,
                                                   void* __restrict__ C) {
  __shared__ __align__(16) __hip_bfloat16 As[128 * 32];
  __shared__ __align__(16) __hip_bfloat16 Bs[128 * 32];
  const int tid = threadIdx.x;
  const int lane = tid & 63, w = tid >> 6;
  const int m0 = blockIdx.y * 128, n0 = blockIdx.x * 128;
  const int wm = (w >> 1) * 64, wn = (w & 1) * 64;
  const int r = lane & 15, q = lane >> 4;

  f32x4 acc[4][4];
  const f32x4 zz = {0.f, 0.f, 0.f, 0.f};
  for (int i = 0; i < 4; i++)
    for (int j = 0; j < 4; j++) acc[i][j] = zz;

  for (int k0 = 0; k0 < K; k0 += 32) {
    for (int i = 0; i < 2; i++) {
      const int c = i * 256 + tid;
      const int row = c >> 2, kb = (c & 3) * 8;
      gl_lds16(A + (size_t)(m0 + row) * K + (k0 + kb), As + c * 8);
      gl_lds16(B + (size_t)(n0 + row) * K + (k0 + kb), Bs + c * 8);
    }
    __syncthreads();
    bf16x8 af[4], bfr[4];
    for (int mi = 0; mi < 4; mi++)
      af[mi] = *(const bf16x8*)(As + (wm + mi * 16 + r) * 32 + q * 8);
    for (int ni = 0; ni < 4; ni++)
      bfr[ni] = *(const bf16x8*)(Bs + (wn + ni * 16 + r) * 32 + q * 8);
    for (int mi = 0; mi < 4; mi++)
      for (int ni = 0; ni < 4; ni++)
        acc[mi][ni] = __builtin_amdgcn_mfma_f32_16x16x32_bf16(af[mi], bfr[ni], acc[mi][ni], 0, 0, 0);
    __syncthreads();
  }

  for (int mi = 0; mi < 4; mi++)
    for (int ni = 0; ni < 4; ni++)
      for (int j = 0; j < 4; j++) {
        const int gm = m0 + wm + mi * 16 + q * 4 + j;
        const int gn = n0 + wn + ni * 16 + r;
        float v = acc[mi][ni][j];
        const size_t idx = (size_t)gm * N + gn;
        if (EPI == 0) {
          ((__hip_bfloat16*)C)[idx] = f2bf(v);
        } else if (EPI == 1) {
          ((float*)C)[idx] = v + aux[idx];
        } else if (EPI == 2) {
          v = v / (1.0f + expf(-v));
          ((__hip_bfloat16*)C)[idx] = f2bf(v);
        } else {
          ((float*)C)[idx] = v + aux[idx];
        }
      }
}

// ---------------- attention 16-key chunk: all-register, no cross-lane ----------------
// S^T = K·Q^T via mfma_16x16x32 (A=K rows=keys, B=Q rows=qrows):
//   lane(c=lane&15, q=lane>>4) holds S^T[key=4q+j][qrow=c], j=0..3.
// After exp2, that register IS the B-fragment of mfma_16x16x16 (k=quad*4+j) for
//   O^T[d][qrow] += V^T[d][key] · P^T[key][qrow]   (A = vt rows, b64 loads).
template <bool CHECK>
__device__ __forceinline__ void attn_chunk(int key0c, int c, int q,
                                           const __hip_bfloat16* Kbase,
                                           const __hip_bfloat16* Vbase,
                                           const float* bias_k, float scale2, float cl,
                                           const bf16x8& qf0, const bf16x8& qf1,
                                           f32x4* o, float& lsp) {
  const f32x4 zz = {0.f, 0.f, 0.f, 0.f};
  const __hip_bfloat16* kr = Kbase + (size_t)(key0c + c) * QKV_LD + q * 8;
  bf16x8 k0 = *(const bf16x8*)kr;
  bf16x8 k1 = *(const bf16x8*)(kr + 32);
  const float4 bb = *(const float4*)(bias_k + key0c + q * 4);  // keys 4q..4q+3 (broadcast/quad)

  f32x4 d = zz;
  d = __builtin_amdgcn_mfma_f32_16x16x32_bf16(k0, qf0, d, 0, 0, 0);
  d = __builtin_amdgcn_mfma_f32_16x16x32_bf16(k1, qf1, d, 0, 0, 0);

  bf16x4 pk;
#pragma unroll
  for (int j = 0; j < 4; j++) {
    float v = fmaf(d[j], scale2, ((const float*)&bb)[j] - cl);  // log2-domain, <= 0
    if (CHECK) v = (q * 4 + j <= c) ? v : -INFINITY;
    const float p = exp2f(v);
    lsp += p;
    pk[j] = bfbits(p);
  }

#pragma unroll
  for (int cc = 0; cc < 4; cc++) {
    const bf16x4 vf = *(const bf16x4*)(Vbase + (size_t)(cc * 16 + c) * L_SEQ + key0c + q * 4);
    o[cc] = __builtin_amdgcn_mfma_f32_16x16x16bf16_1k(vf, pk, o[cc], 0, 0, 0);
  }
}

// grid: 2048 blocks x 128 threads (2 independent waves); wave owns 16 q-rows.
// XCD swizzle: XCD = blk&7; each XCD serves 2 heads (K/V/bias ~2MB -> fits 4MB L2).
__global__ __launch_bounds__(128, 4) void attn_kernel(const __hip_bfloat16* __restrict__ qkv,
                                                      const __hip_bfloat16* __restrict__ vt,
                                                      const float* __restrict__ ts,
                                                      const float* __restrict__ bias,
                                                      const float* __restrict__ kmax,
                                                      const float* __restrict__ decay_rate,
                                                      __hip_bfloat16* __restrict__ out) {
  const int blk = blockIdx.x;
  const int t = blk >> 3;                       // 0..255
  const int bh = (blk & 7) * 2 + (t & 1);       // 2 heads per XCD
  const int strip = t >> 1;                     // 0..127, heavy-first
  const int b = bh >> 3, h = bh & 7;
  const int tid = threadIdx.x, lane = tid & 63, w = tid >> 6;
  const int lw0 = (127 - strip) * 32 + w * 16;
  const int c = lane & 15, q = lane >> 4;

  const float LOG2E = 1.4426950408889634f;
  const float scale2 = 0.125f * LOG2E;
  const float dfac = log1pf(expf(decay_rate[h])) * (1.0f / 24.0f) * LOG2E;

  bf16x8 qf0, qf1;
  {
    const __hip_bfloat16* qrow = qkv + (size_t)(b * L_SEQ + lw0 + c) * QKV_LD + h * 64 + q * 8;
    qf0 = *(const bf16x8*)qrow;
    qf1 = *(const bf16x8*)(qrow + 32);
  }
  // per-row score bound: m = |q_row| * max|k| * scale2 ; cl = bq_row + m_row
  float sumsq = 0.f;
  for (int i = 0; i < 8; i++) {
    const float a = bf2f(((const __hip_bfloat16*)&qf0)[i]);
    const float bb = bf2f(((const __hip_bfloat16*)&qf1)[i]);
    sumsq = fmaf(a, a, sumsq);
    sumsq = fmaf(bb, bb, sumsq);
  }
  sumsq += __shfl_xor(sumsq, 16);
  sumsq += __shfl_xor(sumsq, 32);
  const float mrow = sqrtf(sumsq) * kmax[bh] * scale2;
  const float cl = fmaf(dfac, ts[b * L_SEQ + lw0 + c], mrow);

  const __hip_bfloat16* Kbase = qkv + (size_t)b * L_SEQ * QKV_LD + 512 + h * 64;
  const __hip_bfloat16* Vbase = vt + (size_t)bh * 64 * L_SEQ;
  const float* bias_k = bias + bh * L_SEQ;

  const f32x4 zz = {0.f, 0.f, 0.f, 0.f};
  f32x4 o[4];
  for (int cc = 0; cc < 4; cc++) o[cc] = zz;
  float lsp = 0.f;

  const int nf = lw0 >> 4;  // full 16-key chunks (no causal check)
  int ch = 0;
  for (; ch + 4 <= nf; ch += 4) {  // 4-way unrolled: independent chunk chains
    attn_chunk<false>((ch + 0) << 4, c, q, Kbase, Vbase, bias_k, scale2, cl, qf0, qf1, o, lsp);
    attn_chunk<false>((ch + 1) << 4, c, q, Kbase, Vbase, bias_k, scale2, cl, qf0, qf1, o, lsp);
    attn_chunk<false>((ch + 2) << 4, c, q, Kbase, Vbase, bias_k, scale2, cl, qf0, qf1, o, lsp);
    attn_chunk<false>((ch + 3) << 4, c, q, Kbase, Vbase, bias_k, scale2, cl, qf0, qf1, o, lsp);
  }
  for (; ch < nf; ch++)
    attn_chunk<false>(ch << 4, c, q, Kbase, Vbase, bias_k, scale2, cl, qf0, qf1, o, lsp);
  attn_chunk<true>(nf << 4, c, q, Kbase, Vbase, bias_k, scale2, cl, qf0, qf1, o, lsp);

  // row-sum: lane holds partial over its 4 keys per chunk -> reduce over quads
  lsp += __shfl_xor(lsp, 16);
  lsp += __shfl_xor(lsp, 32);
  const float inv = 1.0f / lsp;

  // O^T: lane holds qrow=c, d = cc*16 + 4q + j -> 4 packed 8B stores
  __hip_bfloat16* orow = out + (size_t)(b * L_SEQ + lw0 + c) * D_MODEL + h * 64;
#pragma unroll
  for (int cc = 0; cc < 4; cc++) {
    bf16x4 ov;
#pragma unroll
    for (int j = 0; j < 4; j++) ov[j] = bfbits(o[cc][j] * inv);
    *(bf16x4*)(orow + cc * 16 + q * 4) = ov;
  }
}

// ---------------- Launch ----------------
extern "C" void kernel_launch(void* const* d_in, const int* in_sizes, int n_in,
                              void* d_out, int out_size, void* d_ws, size_t ws_size,
                              hipStream_t stream) {
  const float* x = (const float*)d_in[0];
  const float* ts = (const float*)d_in[1];
  const float* mask = (const float*)d_in[2];
  const float* ln1_g = (const float*)d_in[3];
  const float* ln1_b = (const float*)d_in[4];
  const float* w_qkv = (const float*)d_in[5];
  const float* w_out = (const float*)d_in[6];
  const float* decay = (const float*)d_in[7];
  const float* ln2_g = (const float*)d_in[8];
  const float* ln2_b = (const float*)d_in[9];
  const float* w_ff1 = (const float*)d_in[10];
  const float* w_ff2 = (const float*)d_in[11];

  char* ws = (char*)d_ws;
  // layout (bytes):
  //   [0, 6M)    weights bf16
  //   [6M, 14M)  xn (dead after gemm0) -> vt overlays
  //   [14M, 38M) qkv (dead after attn)
  //   [38M, 46M) attnout -> h
  //   [46M, 62M) x2 (fp32)
  //   [62M, +256K) key bias fp32 ; then kmax[16]
  //   ff1out overlays [6M, 38M)
  __hip_bfloat16* wqkv_b = (__hip_bfloat16*)(ws + 0);
  __hip_bfloat16* wout_b = (__hip_bfloat16*)(ws + 1572864);
  __hip_bfloat16* wff1_b = (__hip_bfloat16*)(ws + 2097152);
  __hip_bfloat16* wff2_b = (__hip_bfloat16*)(ws + 4194304);
  __hip_bfloat16* xn = (__hip_bfloat16*)(ws + 6291456);
  __hip_bfloat16* vt = (__hip_bfloat16*)(ws + 6291456);
  __hip_bfloat16* qkv = (__hip_bfloat16*)(ws + 14680064);
  __hip_bfloat16* attnout = (__hip_bfloat16*)(ws + 39845888);
  __hip_bfloat16* h = attnout;
  __hip_bfloat16* ff1out = (__hip_bfloat16*)(ws + 6291456);
  float* x2 = (float*)(ws + 48234496);
  float* biasbuf = (float*)(ws + 65011712);
  float* kmaxbuf = (float*)(ws + 65273856);
  float* out = (float*)d_out;

  const int M = 2 * L_SEQ;  // 8192

  cvt_kernel<<<dim3(768), dim3(256), 0, stream>>>(w_qkv, wqkv_b, 196608);
  cvt_kernel<<<dim3(256), dim3(256), 0, stream>>>(w_out, wout_b, 65536);
  cvt_kernel<<<dim3(1024), dim3(256), 0, stream>>>(w_ff1, wff1_b, 262144);
  cvt_kernel<<<dim3(1024), dim3(256), 0, stream>>>(w_ff2, wff2_b, 262144);

  bias_kernel<<<dim3(256), dim3(256), 0, stream>>>(ts, mask, decay, biasbuf);
  ln_kernel<<<dim3(M), dim3(256), 0, stream>>>(x, ln1_g, ln1_b, xn);
  gemm_kernel<0><<<dim3(12, 64), dim3(256), 0, stream>>>(xn, wqkv_b, M, 1536, 512, nullptr, qkv);
  vtrans_kernel<<<dim3(2048), dim3(256), 0, stream>>>(qkv, vt);
  kmax_kernel<<<dim3(16), dim3(256), 0, stream>>>(qkv, kmaxbuf);
  attn_kernel<<<dim3(2048), dim3(128), 0, stream>>>(qkv, vt, ts, biasbuf, kmaxbuf, decay, attnout);
  gemm_kernel<1><<<dim3(4, 64), dim3(256), 0, stream>>>(attnout, wout_b, M, 512, 512, x, x2);
  ln_kernel<<<dim3(M), dim3(256), 0, stream>>>(x2, ln2_g, ln2_b, h);
  gemm_kernel<2><<<dim3(16, 64), dim3(256), 0, stream>>>(h, wff1_b, M, 2048, 512, nullptr, ff1out);
  gemm_kernel<3><<<dim3(4, 64), dim3(256), 0, stream>>>(ff1out, wff2_b, M, 512, 2048, x2, out);
}

// Round 9
// 543.946 us; speedup vs baseline: 1.2280x; 1.2280x over previous
//
#include <hip/hip_runtime.h>
#include <hip/hip_bf16.h>
#include <cmath>

// SparseAttentionBlock: B=2, L=4096, D=512, H=8, dh=64
// Inputs/outputs fp32; internal GEMM pipeline bf16; residual spine fp32.
// Attention: m97-style LDS staging (global_load_lds + barriers) + S^T=K.Q^T
// register path (P^T C-layout == 16x16x16 PV B-fragment). XOR-swizzled LDS.

#define L_SEQ 4096
#define D_MODEL 512
#define N_HEADS 8
#define D_HEAD 64
#define QKV_LD 1536

typedef __attribute__((ext_vector_type(8))) short bf16x8;
typedef __attribute__((ext_vector_type(4))) short bf16x4;
typedef __attribute__((ext_vector_type(4))) float f32x4;

__device__ __forceinline__ __hip_bfloat16 f2bf(float v) { return __float2bfloat16(v); }
__device__ __forceinline__ float bf2f(__hip_bfloat16 v) { return __bfloat162float(v); }
__device__ __forceinline__ short bfbits(float v) {
  __hip_bfloat16 t = __float2bfloat16(v);
  return *(short*)&t;
}

__device__ __forceinline__ void gl_lds16(const __hip_bfloat16* g, __hip_bfloat16* l) {
  __builtin_amdgcn_global_load_lds((__attribute__((address_space(1))) void*)g,
                                   (__attribute__((address_space(3))) void*)l, 16, 0, 0);
}
__device__ __forceinline__ void gl_lds4(const float* g, float* l) {
  __builtin_amdgcn_global_load_lds((__attribute__((address_space(1))) void*)g,
                                   (__attribute__((address_space(3))) void*)l, 4, 0, 0);
}

// ---------------- fp32 -> bf16 convert (weights) ----------------
__global__ __launch_bounds__(256) void cvt_kernel(const float* __restrict__ src,
                                                  __hip_bfloat16* __restrict__ dst, int n4) {
  const int i = blockIdx.x * 256 + threadIdx.x;
  if (i < n4) {
    const float4 v = ((const float4*)src)[i];
    dst[4 * i + 0] = f2bf(v.x);
    dst[4 * i + 1] = f2bf(v.y);
    dst[4 * i + 2] = f2bf(v.z);
    dst[4 * i + 3] = f2bf(v.w);
  }
}

// ---------------- LayerNorm: fp32 in -> bf16 out ----------------
__global__ __launch_bounds__(256) void ln_kernel(const float* __restrict__ x,
                                                 const float* __restrict__ g,
                                                 const float* __restrict__ b,
                                                 __hip_bfloat16* __restrict__ out) {
  const int row = blockIdx.x;
  const int t = threadIdx.x;
  const float* xr = x + (size_t)row * D_MODEL;
  float v0 = xr[t];
  float v1 = xr[t + 256];
  float s = v0 + v1;
  float qq = v0 * v0 + v1 * v1;
  for (int off = 32; off > 0; off >>= 1) {
    s += __shfl_xor(s, off);
    qq += __shfl_xor(qq, off);
  }
  __shared__ float red[8];
  const int wid = t >> 6;
  if ((t & 63) == 0) { red[wid] = s; red[4 + wid] = qq; }
  __syncthreads();
  s = red[0] + red[1] + red[2] + red[3];
  qq = red[4] + red[5] + red[6] + red[7];
  const float mu = s * (1.0f / 512.0f);
  const float var = fmaxf(qq * (1.0f / 512.0f) - mu * mu, 0.0f);
  const float rstd = rsqrtf(var + 1e-5f);
  __hip_bfloat16* orow = out + (size_t)row * D_MODEL;
  orow[t] = f2bf((v0 - mu) * rstd * g[t] + b[t]);
  orow[t + 256] = f2bf((v1 - mu) * rstd * g[t + 256] + b[t + 256]);
}

// ---------------- V transpose: qkv V-region -> vt[b,h,dh,L] ----------------
__global__ __launch_bounds__(256) void vtrans_kernel(const __hip_bfloat16* __restrict__ qkv,
                                                     __hip_bfloat16* __restrict__ vt) {
  const int gid = blockIdx.x * 256 + threadIdx.x;  // 2*64*4096 threads exactly
  const int l = gid & 4095;
  const int bg = gid >> 12;
  const int b = bg >> 6, g = bg & 63;
  const int h = g >> 3, dg = (g & 7) * 8;
  const __hip_bfloat16* src = qkv + (size_t)(b * L_SEQ + l) * QKV_LD + 1024 + h * 64 + dg;
  bf16x8 v = *(const bf16x8*)src;
  const size_t dbase = (size_t)((b * 8 + h) * 64 + dg) * L_SEQ + l;
  for (int j = 0; j < 8; j++)
    vt[dbase + (size_t)j * L_SEQ] = ((const __hip_bfloat16*)&v)[j];  // coalesced over l
}

// ---------------- kmax: per (b,h) max ||k_row||_2 ----------------
__global__ __launch_bounds__(256) void kmax_kernel(const __hip_bfloat16* __restrict__ qkv,
                                                   float* __restrict__ kmax) {
  const int bh = blockIdx.x;
  const int b = bh >> 3, h = bh & 7;
  const __hip_bfloat16* Kb = qkv + (size_t)b * L_SEQ * QKV_LD + 512 + h * 64;
  float mx = 0.f;
  for (int l = threadIdx.x; l < L_SEQ; l += 256) {
    const bf16x8* row = (const bf16x8*)(Kb + (size_t)l * QKV_LD);
    float ss = 0.f;
    for (int i = 0; i < 8; i++) {
      bf16x8 v = row[i];
      for (int k = 0; k < 8; k++) {
        const float f = bf2f(((const __hip_bfloat16*)&v)[k]);
        ss = fmaf(f, f, ss);
      }
    }
    mx = fmaxf(mx, ss);
  }
  for (int off = 32; off > 0; off >>= 1) mx = fmaxf(mx, __shfl_xor(mx, off));
  __shared__ float red[4];
  if ((threadIdx.x & 63) == 0) red[threadIdx.x >> 6] = mx;
  __syncthreads();
  if (threadIdx.x == 0)
    kmax[bh] = sqrtf(fmaxf(fmaxf(red[0], red[1]), fmaxf(red[2], red[3])));
}

// ---------------- key bias: bias[bh][l] = mask ? dfac_h * ts : -1e30 ----------------
__global__ __launch_bounds__(256) void bias_kernel(const float* __restrict__ ts,
                                                   const float* __restrict__ mask,
                                                   const float* __restrict__ decay_rate,
                                                   float* __restrict__ bias) {
  const int idx = blockIdx.x * 256 + threadIdx.x;  // 16*4096 threads
  const int bh = idx >> 12, l = idx & 4095;
  const int b = bh >> 3, h = bh & 7;
  const float LOG2E = 1.4426950408889634f;
  const float dfac = log1pf(expf(decay_rate[h])) * (1.0f / 24.0f) * LOG2E;
  const float m = mask[b * L_SEQ + l];
  bias[idx] = (m != 0.f) ? dfac * ts[b * L_SEQ + l] : -1e30f;
}

// ---------------- GEMM: C[M,N] = A[M,K] @ B[N,K]^T, bf16 in, fp32 accum ----------------
// EPI 0: store bf16   1: += aux(fp32), store fp32   2: silu, store bf16   3: += aux(fp32), store fp32
template <int EPI>
__global__ __launch_bounds__(256) void gemm_kernel(const __hip_bfloat16* __restrict__ A,
                                                   const __hip_bfloat16* __restrict__ B,
                                                   int M, int N, int K,
                                                   const float* __restrict__ aux,
                                                   void* __restrict__ C) {
  __shared__ __align__(16) __hip_bfloat16 As[128 * 32];
  __shared__ __align__(16) __hip_bfloat16 Bs[128 * 32];
  const int tid = threadIdx.x;
  const int lane = tid & 63, w = tid >> 6;
  const int m0 = blockIdx.y * 128, n0 = blockIdx.x * 128;
  const int wm = (w >> 1) * 64, wn = (w & 1) * 64;
  const int r = lane & 15, q = lane >> 4;

  f32x4 acc[4][4];
  const f32x4 zz = {0.f, 0.f, 0.f, 0.f};
  for (int i = 0; i < 4; i++)
    for (int j = 0; j < 4; j++) acc[i][j] = zz;

  for (int k0 = 0; k0 < K; k0 += 32) {
    for (int i = 0; i < 2; i++) {
      const int c = i * 256 + tid;
      const int row = c >> 2, kb = (c & 3) * 8;
      gl_lds16(A + (size_t)(m0 + row) * K + (k0 + kb), As + c * 8);
      gl_lds16(B + (size_t)(n0 + row) * K + (k0 + kb), Bs + c * 8);
    }
    __syncthreads();
    bf16x8 af[4], bfr[4];
    for (int mi = 0; mi < 4; mi++)
      af[mi] = *(const bf16x8*)(As + (wm + mi * 16 + r) * 32 + q * 8);
    for (int ni = 0; ni < 4; ni++)
      bfr[ni] = *(const bf16x8*)(Bs + (wn + ni * 16 + r) * 32 + q * 8);
    for (int mi = 0; mi < 4; mi++)
      for (int ni = 0; ni < 4; ni++)
        acc[mi][ni] = __builtin_amdgcn_mfma_f32_16x16x32_bf16(af[mi], bfr[ni], acc[mi][ni], 0, 0, 0);
    __syncthreads();
  }

  for (int mi = 0; mi < 4; mi++)
    for (int ni = 0; ni < 4; ni++)
      for (int j = 0; j < 4; j++) {
        const int gm = m0 + wm + mi * 16 + q * 4 + j;
        const int gn = n0 + wn + ni * 16 + r;
        float v = acc[mi][ni][j];
        const size_t idx = (size_t)gm * N + gn;
        if (EPI == 0) {
          ((__hip_bfloat16*)C)[idx] = f2bf(v);
        } else if (EPI == 1) {
          ((float*)C)[idx] = v + aux[idx];
        } else if (EPI == 2) {
          v = v / (1.0f + expf(-v));
          ((__hip_bfloat16*)C)[idx] = f2bf(v);
        } else {
          ((float*)C)[idx] = v + aux[idx];
        }
      }
}

// ---------------- attention: per-group QK + P (S^T trick, fixed-bound softmax) -------
__device__ __forceinline__ void qk_group(const bf16x8& k0, const bf16x8& k1,
                                         const bf16x8& q0, const bf16x8& q1,
                                         const float4& bb, float clg, bool chk,
                                         int c, int q, float scale2,
                                         bf16x4& pk, float& lsg) {
  f32x4 d = {0.f, 0.f, 0.f, 0.f};
  d = __builtin_amdgcn_mfma_f32_16x16x32_bf16(k0, q0, d, 0, 0, 0);
  d = __builtin_amdgcn_mfma_f32_16x16x32_bf16(k1, q1, d, 0, 0, 0);
#pragma unroll
  for (int j = 0; j < 4; j++) {
    float v = fmaf(d[j], scale2, ((const float*)&bb)[j] - clg);
    if (chk && (q * 4 + j > c)) v = -INFINITY;
    const float p = exp2f(v);
    lsg += p;
    pk[j] = bfbits(p);
  }
}

// grid: 512 blocks = 32 q-strips(128 rows) x 16 bh, heavy-first, XCD-swizzled.
// block: 256 threads = 4 waves; wave owns 32 q-rows (2 groups of 16).
// Per 128-key tile: stage K(128x64), V^T(64x128), bias(128) into LDS via
// global_load_lds with XOR source-block swizzle (2-way max conflicts), then
// all-register chunk compute (no P LDS round-trip).
__global__ __launch_bounds__(256, 3) void attn_kernel(const __hip_bfloat16* __restrict__ qkv,
                                                      const __hip_bfloat16* __restrict__ vt,
                                                      const float* __restrict__ ts,
                                                      const float* __restrict__ bias,
                                                      const float* __restrict__ kmax,
                                                      const float* __restrict__ decay_rate,
                                                      __hip_bfloat16* __restrict__ out) {
  __shared__ __align__(16) __hip_bfloat16 Ks[128 * 64];
  __shared__ __align__(16) __hip_bfloat16 Vt[64 * 128];
  __shared__ __align__(16) float Bs[128];

  const int blk = blockIdx.x;
  const int qb = 31 - (blk >> 4);                // heavy strips first
  const int bh = (blk & 7) * 2 + ((blk >> 3) & 1);  // 2 heads per XCD
  const int b = bh >> 3, h = bh & 7;
  const int tid = threadIdx.x, l = tid & 63, w = tid >> 6;
  const int c = l & 15, q = l >> 4;

  const int lw0 = qb * 128 + w * 32;  // group 0 rows lw0..+15, group 1 lw0+16..+31
  const int lw1 = lw0 + 16;

  const float LOG2E = 1.4426950408889634f;
  const float scale2 = 0.125f * LOG2E;
  const float dfac = log1pf(expf(decay_rate[h])) * (1.0f / 24.0f) * LOG2E;
  const float kmx = kmax[bh];

  // Q fragments (B-operand layout): lane(c,q) holds Q[row=lw?+c][dh q*8..+7]
  bf16x8 q00, q01, q10, q11;
  {
    const __hip_bfloat16* qr0 = qkv + (size_t)(b * L_SEQ + lw0 + c) * QKV_LD + h * 64 + q * 8;
    const __hip_bfloat16* qr1 = qkv + (size_t)(b * L_SEQ + lw1 + c) * QKV_LD + h * 64 + q * 8;
    q00 = *(const bf16x8*)qr0;
    q01 = *(const bf16x8*)(qr0 + 32);
    q10 = *(const bf16x8*)qr1;
    q11 = *(const bf16x8*)(qr1 + 32);
  }
  // fixed per-row score bounds
  float cl0, cl1;
  {
    float s0 = 0.f, s1 = 0.f;
    for (int i = 0; i < 8; i++) {
      float a = bf2f(((const __hip_bfloat16*)&q00)[i]), bb2 = bf2f(((const __hip_bfloat16*)&q01)[i]);
      s0 = fmaf(a, a, s0); s0 = fmaf(bb2, bb2, s0);
      a = bf2f(((const __hip_bfloat16*)&q10)[i]); bb2 = bf2f(((const __hip_bfloat16*)&q11)[i]);
      s1 = fmaf(a, a, s1); s1 = fmaf(bb2, bb2, s1);
    }
    s0 += __shfl_xor(s0, 16); s0 += __shfl_xor(s0, 32);
    s1 += __shfl_xor(s1, 16); s1 += __shfl_xor(s1, 32);
    cl0 = fmaf(dfac, ts[b * L_SEQ + lw0 + c], sqrtf(s0) * kmx * scale2);
    cl1 = fmaf(dfac, ts[b * L_SEQ + lw1 + c], sqrtf(s1) * kmx * scale2);
  }

  const __hip_bfloat16* Kg = qkv + (size_t)b * L_SEQ * QKV_LD + 512 + h * 64;
  const __hip_bfloat16* Vg = vt + (size_t)bh * 64 * L_SEQ;
  const float* bias_k = bias + bh * L_SEQ;

  const f32x4 zz = {0.f, 0.f, 0.f, 0.f};
  f32x4 o0[4], o1[4];
  for (int cc = 0; cc < 4; cc++) { o0[cc] = zz; o1[cc] = zz; }
  float ls0 = 0.f, ls1 = 0.f;

  const int ntiles = qb + 1;
  for (int kt = 0; kt < ntiles; kt++) {
    const int key0 = kt << 7;
    // ---- stage (XOR source-block swizzle so LDS image is bank-conflict-free) ----
#pragma unroll
    for (int i = 0; i < 4; i++) {
      const int rl = 32 * w + i * 8 + (l >> 3);          // K row 0..127
      const int pbk = (l & 7) ^ (rl & 7);
      gl_lds16(Kg + (size_t)(key0 + rl) * QKV_LD + pbk * 8, Ks + (32 * w + i * 8) * 64 + l * 8);
      const int dl = 16 * w + i * 4 + (l >> 4);          // V^T row 0..63
      const int pbv = (l & 15) ^ (dl & 7);
      gl_lds16(Vg + (size_t)dl * L_SEQ + key0 + pbv * 8, Vt + (16 * w + i * 4) * 128 + l * 8);
    }
    if (w == 0) {
      gl_lds4(bias_k + key0 + l, Bs + l);
      gl_lds4(bias_k + key0 + 64 + l, Bs + 64 + l);
    }
    __syncthreads();

    // ---- compute: 8 chunks of 16 keys ----
#pragma unroll
    for (int ch = 0; ch < 8; ch++) {
      const int key0c = key0 + (ch << 4);
      if (key0c > lw1) break;  // wave-uniform
      const float4 bb = *(const float4*)(Bs + (ch << 4) + (q << 2));
      const __hip_bfloat16* kp = Ks + ((ch << 4) + c) * 64;
      const bf16x8 k0 = *(const bf16x8*)(kp + ((q ^ (c & 7)) << 3));
      const bf16x8 k1 = *(const bf16x8*)(kp + (((q + 4) ^ (c & 7)) << 3));

      bf16x4 pk1;
      qk_group(k0, k1, q10, q11, bb, cl1, key0c == lw1, c, q, scale2, pk1, ls1);
      const bool a0 = key0c <= lw0;
      bf16x4 pk0;
      if (a0) qk_group(k0, k1, q00, q01, bb, cl0, key0c == lw0, c, q, scale2, pk0, ls0);

#pragma unroll
      for (int cc = 0; cc < 4; cc++) {
        const bf16x4 vf = *(const bf16x4*)(Vt + ((cc << 4) + c) * 128 +
                                           (((2 * ch + (q >> 1)) ^ (c & 7)) << 3) + ((q & 1) << 2));
        o1[cc] = __builtin_amdgcn_mfma_f32_16x16x16bf16_1k(vf, pk1, o1[cc], 0, 0, 0);
        if (a0) o0[cc] = __builtin_amdgcn_mfma_f32_16x16x16bf16_1k(vf, pk0, o0[cc], 0, 0, 0);
      }
    }
    __syncthreads();
  }

  // ---- epilogue: reduce ls over quads, normalize, packed 8B stores ----
  ls0 += __shfl_xor(ls0, 16); ls0 += __shfl_xor(ls0, 32);
  ls1 += __shfl_xor(ls1, 16); ls1 += __shfl_xor(ls1, 32);
  const float inv0 = 1.0f / ls0, inv1 = 1.0f / ls1;
  __hip_bfloat16* or0 = out + (size_t)(b * L_SEQ + lw0 + c) * D_MODEL + h * 64;
  __hip_bfloat16* or1 = out + (size_t)(b * L_SEQ + lw1 + c) * D_MODEL + h * 64;
#pragma unroll
  for (int cc = 0; cc < 4; cc++) {
    bf16x4 v0, v1;
#pragma unroll
    for (int j = 0; j < 4; j++) {
      v0[j] = bfbits(o0[cc][j] * inv0);
      v1[j] = bfbits(o1[cc][j] * inv1);
    }
    *(bf16x4*)(or0 + cc * 16 + q * 4) = v0;
    *(bf16x4*)(or1 + cc * 16 + q * 4) = v1;
  }
}

// ---------------- Launch ----------------
extern "C" void kernel_launch(void* const* d_in, const int* in_sizes, int n_in,
                              void* d_out, int out_size, void* d_ws, size_t ws_size,
                              hipStream_t stream) {
  const float* x = (const float*)d_in[0];
  const float* ts = (const float*)d_in[1];
  const float* mask = (const float*)d_in[2];
  const float* ln1_g = (const float*)d_in[3];
  const float* ln1_b = (const float*)d_in[4];
  const float* w_qkv = (const float*)d_in[5];
  const float* w_out = (const float*)d_in[6];
  const float* decay = (const float*)d_in[7];
  const float* ln2_g = (const float*)d_in[8];
  const float* ln2_b = (const float*)d_in[9];
  const float* w_ff1 = (const float*)d_in[10];
  const float* w_ff2 = (const float*)d_in[11];

  char* ws = (char*)d_ws;
  // layout (bytes):
  //   [0, 6M)    weights bf16
  //   [6M, 14M)  xn (dead after gemm0) -> vt overlays
  //   [14M, 38M) qkv (dead after attn)
  //   [38M, 46M) attnout -> h
  //   [46M, 62M) x2 (fp32)
  //   [62M, +256K) key bias fp32 ; then kmax[16]
  //   ff1out overlays [6M, 38M)
  __hip_bfloat16* wqkv_b = (__hip_bfloat16*)(ws + 0);
  __hip_bfloat16* wout_b = (__hip_bfloat16*)(ws + 1572864);
  __hip_bfloat16* wff1_b = (__hip_bfloat16*)(ws + 2097152);
  __hip_bfloat16* wff2_b = (__hip_bfloat16*)(ws + 4194304);
  __hip_bfloat16* xn = (__hip_bfloat16*)(ws + 6291456);
  __hip_bfloat16* vt = (__hip_bfloat16*)(ws + 6291456);
  __hip_bfloat16* qkv = (__hip_bfloat16*)(ws + 14680064);
  __hip_bfloat16* attnout = (__hip_bfloat16*)(ws + 39845888);
  __hip_bfloat16* h = attnout;
  __hip_bfloat16* ff1out = (__hip_bfloat16*)(ws + 6291456);
  float* x2 = (float*)(ws + 48234496);
  float* biasbuf = (float*)(ws + 65011712);
  float* kmaxbuf = (float*)(ws + 65273856);
  float* out = (float*)d_out;

  const int M = 2 * L_SEQ;  // 8192

  cvt_kernel<<<dim3(768), dim3(256), 0, stream>>>(w_qkv, wqkv_b, 196608);
  cvt_kernel<<<dim3(256), dim3(256), 0, stream>>>(w_out, wout_b, 65536);
  cvt_kernel<<<dim3(1024), dim3(256), 0, stream>>>(w_ff1, wff1_b, 262144);
  cvt_kernel<<<dim3(1024), dim3(256), 0, stream>>>(w_ff2, wff2_b, 262144);

  bias_kernel<<<dim3(256), dim3(256), 0, stream>>>(ts, mask, decay, biasbuf);
  ln_kernel<<<dim3(M), dim3(256), 0, stream>>>(x, ln1_g, ln1_b, xn);
  gemm_kernel<0><<<dim3(12, 64), dim3(256), 0, stream>>>(xn, wqkv_b, M, 1536, 512, nullptr, qkv);
  vtrans_kernel<<<dim3(2048), dim3(256), 0, stream>>>(qkv, vt);
  kmax_kernel<<<dim3(16), dim3(256), 0, stream>>>(qkv, kmaxbuf);
  attn_kernel<<<dim3(512), dim3(256), 0, stream>>>(qkv, vt, ts, biasbuf, kmaxbuf, decay, attnout);
  gemm_kernel<1><<<dim3(4, 64), dim3(256), 0, stream>>>(attnout, wout_b, M, 512, 512, x, x2);
  ln_kernel<<<dim3(M), dim3(256), 0, stream>>>(x2, ln2_g, ln2_b, h);
  gemm_kernel<2><<<dim3(16, 64), dim3(256), 0, stream>>>(h, wff1_b, M, 2048, 512, nullptr, ff1out);
  gemm_kernel<3><<<dim3(4, 64), dim3(256), 0, stream>>>(ff1out, wff2_b, M, 512, 2048, x2, out);
}